// Round 14
// baseline (1628.593 us; speedup 1.0000x reference)
//
#include <hip/hip_runtime.h>
#include <hip/hip_bf16.h>

#define NVOC 50257
#define HID 256
#define NLAYER 2
#define SEQ 128
#define BATCH 16
#define GUARD (1 << 18)
#define DGUARD (1 << 15)
#define NCHUNK 197                    // ceil(NVOC/256)
#define DECBLKS (32 * NCHUNK)
#define FSTR 16                       // flag words per timestep
#define REGK 6                        // kk < REGK -> weight frag in registers
#define WLDS_BYTES (32 * 16 * 256)    // 32 frags/lane * 16B * 256 threads = 128 KB
#define HROW 528                      // 256 bf16 cols (512B) + 16B pad
#define HBUF (16 * HROW)              // 8448 B per h buffer
#define SMEM_BYTES (WLDS_BYTES + 2 * HBUF)   // 147968 <= 160 KB

typedef __bf16 bf16x8 __attribute__((ext_vector_type(8)));
typedef float f32x4 __attribute__((ext_vector_type(4)));
typedef unsigned short u16;
typedef unsigned int u32;
typedef unsigned long long u64;

#define AL64(p)   __hip_atomic_load((const u64*)(p), __ATOMIC_RELAXED, __HIP_MEMORY_SCOPE_AGENT)
#define AS32(p,v) __hip_atomic_store((u32*)(p), (v), __ATOMIC_RELAXED, __HIP_MEMORY_SCOPE_AGENT)
#define AS64(p,v) __hip_atomic_store((u64*)(p), (v), __ATOMIC_RELAXED, __HIP_MEMORY_SCOPE_AGENT)

__device__ __forceinline__ float fsig(float z) { return 1.f / (1.f + __expf(-z)); }
__device__ __forceinline__ float ftanh(float z) {
  const float x = fminf(fmaxf(z, -15.f), 15.f);
  const float e = __expf(2.f * x);
  return (e - 1.f) / (e + 1.f);
}
__device__ __forceinline__ bf16x8 cvt8(const float4 u0, const float4 u1) {
  bf16x8 v;
  v[0] = (__bf16)u0.x; v[1] = (__bf16)u0.y; v[2] = (__bf16)u0.z; v[3] = (__bf16)u0.w;
  v[4] = (__bf16)u1.x; v[5] = (__bf16)u1.y; v[6] = (__bf16)u1.z; v[7] = (__bf16)u1.w;
  return v;
}
__device__ __forceinline__ u64 pk64(float a, float b) {
  return (u64)__builtin_bit_cast(u32, a) | ((u64)__builtin_bit_cast(u32, b) << 32);
}
// lane0-only: wait for 4 flag words at fp
__device__ __forceinline__ void poll4(const u32* fp) {
  int gd = 0;
  for (;;) {
    const u64 m = AL64(fp) & AL64(fp + 2);
    if (((u32)m & (u32)(m >> 32)) != 0u) break;
    if (++gd >= GUARD) break;
  }
}
// lane0-only: wait for 8 flag words at fp
__device__ __forceinline__ void poll8(const u32* fp) {
  int gd = 0;
  for (;;) {
    const u64 m = AL64(fp) & AL64(fp + 2) & AL64(fp + 4) & AL64(fp + 6);
    if (((u32)m & (u32)(m >> 32)) != 0u) break;
    if (++gd >= GUARD) break;
  }
}

// ---------------- flag zero (before mega each call: replay/poison-safe) ----------------
__global__ void zero_kernel(u32* __restrict__ flg) {
  for (int i = threadIdx.x; i < SEQ * FSTR; i += 256) AS32(&flg[i], 0u);
}

// ---------------- XU precompute, TRANSPOSED [t][gatecol][batch], L0 bias folded ----------------
__global__ __launch_bounds__(256) void xu_kernel(
    const int* __restrict__ tokp, const float* __restrict__ embp,
    const float* __restrict__ uF, const float* __restrict__ uI,
    const float* __restrict__ uC, const float* __restrict__ uO,
    const float* __restrict__ bF, const float* __restrict__ bI,
    const float* __restrict__ bC, const float* __restrict__ bO,
    float* __restrict__ XU)
{
  const int tid = threadIdx.x;
  const int lane = tid & 63, wv = tid >> 6, r16 = lane & 15, kgrp = lane >> 4;
  const int t  = blockIdx.x;                  // one timestep per block-x
  const int n0 = blockIdx.y * 256 + wv * 64;
  const float* Ug[4] = {uF, uI, uC, uO};
  const float* Bp[4] = {bF, bI, bC, bO};

  bf16x8 b[4][8];
  float bias[4];
#pragma unroll
  for (int nt = 0; nt < 4; ++nt) {
    const int n = n0 + nt * 16 + r16;
    const float* U = Ug[n >> 8];
    const int c = n & 255;
    bias[nt] = Bp[n >> 8][c];
#pragma unroll
    for (int kk = 0; kk < 8; ++kk) {
      const int kb = kk * 32 + kgrp * 8;
      bf16x8 v;
#pragma unroll
      for (int e = 0; e < 8; ++e) v[e] = (__bf16)U[(size_t)(kb + e) * HID + c];
      b[nt][kk] = v;
    }
  }

  const int tok = tokp[t * BATCH + r16];
  const float* x = embp + (size_t)tok * HID;
  bf16x8 a[8];
#pragma unroll
  for (int kk = 0; kk < 8; ++kk) {
    const int kb = kk * 32 + kgrp * 8;
    a[kk] = cvt8(*reinterpret_cast<const float4*>(x + kb),
                 *reinterpret_cast<const float4*>(x + kb + 4));
  }
#pragma unroll
  for (int nt = 0; nt < 4; ++nt) {
    f32x4 acc = {0.f, 0.f, 0.f, 0.f};
#pragma unroll
    for (int kk = 0; kk < 8; ++kk)
      acc = __builtin_amdgcn_mfma_f32_16x16x32_bf16(a[kk], b[nt][kk], acc, 0, 0, 0);
    const int n = n0 + nt * 16 + r16;
    f32x4 st;
#pragma unroll
    for (int r = 0; r < 4; ++r) st[r] = acc[r] + bias[nt];
    // XU[t][gatecol n][batch kgrp*4 .. +3]
    *reinterpret_cast<f32x4*>(XU + ((size_t)t * 1024 + n) * 16 + kgrp * 4) = st;
  }
}

// ---------------- mega: block-local-recurrence LSTM + XV servers + fused decoder ----------------
// bx0: L0 (full layer, W in 384 VGPR + 128 KB LDS, h0 in LDS; acc init from XU)
// bx1,2: XV (V(t) = h0(t)@U + b1, barrier-free per-wave workers)
// bx3: L1 (same as L0; acc init from V)
// bx>=4: decoder (mb-major, polls L1 wave-flags)
// flags per t (FSTR=16): +0..3 L0 waves, +4..7 L1 waves, +8..15 XV waves.
// Producer flag(t-1) is certified mid-step t: vmcnt(0) there is free (t's loads
// already drained by MFMA deps; t-1 publishes had a full step in flight).
__global__ __launch_bounds__(256, 1) void mega_kernel(
    const float* __restrict__ wF, const float* __restrict__ wI,
    const float* __restrict__ wC, const float* __restrict__ wO,
    const float* __restrict__ uF, const float* __restrict__ uI,
    const float* __restrict__ uC, const float* __restrict__ uO,
    const float* __restrict__ bF, const float* __restrict__ bI,
    const float* __restrict__ bC, const float* __restrict__ bO,
    const float* __restrict__ XU, float* __restrict__ V,
    u32* __restrict__ h0w, u32* __restrict__ h1w,
    u32* __restrict__ flg, const float* __restrict__ dw,
    const float* __restrict__ dbp, float* __restrict__ dout)
{
  extern __shared__ char smem[];
  const int tid  = threadIdx.x;
  const int lane = tid & 63;
  const int wv   = tid >> 6;        // 0..3
  const int r16  = lane & 15;
  const int kgrp = lane >> 4;
  const int bx   = blockIdx.x;
  const size_t logitsN = (size_t)SEQ * BATCH * NVOC;

  if (bx >= 4) {
    // ================= decoder block (mb-major) =================
    const int db = bx - 4;
    const int mb = db / NCHUNK;      // rows [mb*64,+64) = t 4mb..4mb+3
    const int nb = db - mb * NCHUNK; // vocab cols [nb*256,+256)
    const int n0 = nb * 256 + wv * 64;

    bf16x8 b[4][8];
    float bb[4];
#pragma unroll
    for (int nt = 0; nt < 4; ++nt) {
      const int v = n0 + nt * 16 + r16;
      const int vc = (v < NVOC) ? v : (NVOC - 1);
      bb[nt] = dbp[vc];
      const float* bp = dw + (size_t)vc * HID + kgrp * 8;
#pragma unroll
      for (int kk = 0; kk < 8; ++kk)
        b[nt][kk] = cvt8(*reinterpret_cast<const float4*>(bp + kk * 32),
                         *reinterpret_cast<const float4*>(bp + kk * 32 + 4));
    }

    if (tid == 0) {
      const u32* fp = flg + (size_t)(mb * 4 + 3) * FSTR + 4;   // L1 wave flags
      int gd = 0;
      for (;;) {
        const u64 m = AL64(fp) & AL64(fp + 2);
        if (((u32)m & (u32)(m >> 32)) != 0u) break;
        if (++gd >= DGUARD) break;
        __builtin_amdgcn_s_sleep(64);
      }
    }
    __syncthreads();

    const u16* htb = (const u16*)h1w;
#pragma unroll 1
    for (int mt = 0; mt < 4; ++mt) {
      const int m = mb * 64 + mt * 16;
      const u16* ap = htb + ((size_t)(m + r16)) * HID + kgrp * 8;
      bf16x8 a[8];
#pragma unroll
      for (int kk = 0; kk < 8; ++kk)
        a[kk] = *reinterpret_cast<const bf16x8*>(ap + kk * 32);
      f32x4 acc[4];
#pragma unroll
      for (int nt = 0; nt < 4; ++nt) { acc[nt][0]=0.f; acc[nt][1]=0.f; acc[nt][2]=0.f; acc[nt][3]=0.f; }
#pragma unroll
      for (int kk = 0; kk < 8; ++kk)
#pragma unroll
        for (int nt = 0; nt < 4; ++nt)
          acc[nt] = __builtin_amdgcn_mfma_f32_16x16x32_bf16(a[kk], b[nt][kk], acc[nt], 0, 0, 0);
#pragma unroll
      for (int nt = 0; nt < 4; ++nt) {
        const int v = n0 + nt * 16 + r16;
        if (v < NVOC) {
#pragma unroll
          for (int r = 0; r < 4; ++r)
            dout[(size_t)(m + kgrp * 4 + r) * NVOC + v] = acc[nt][r] + bb[nt];
        }
      }
    }
    return;
  }

  const float* Wg[4] = {wF, wI, wC, wO};
  const float* Ug[4] = {uF, uI, uC, uO};
  const float* Bg[4] = {bF, bI, bC, bO};

  if (bx == 1 || bx == 2) {
    // ================= XV server: V(t) = h0(t) @ U + b1 (per-wave, barrier-free) =================
    const int xb = bx - 1;
    const int gbase = xb * 512 + wv * 128;
    bf16x8 ureg[8][8];
    float bias[8];
#pragma unroll
    for (int tile = 0; tile < 8; ++tile) {
      const int gcol = gbase + tile * 16 + r16;
      const float* U = Ug[gcol >> 8];
      const int c = gcol & 255;
      bias[tile] = Bg[gcol >> 8][c];
#pragma unroll
      for (int kk = 0; kk < 8; ++kk) {
        const int kb = kk * 32 + kgrp * 8;
        bf16x8 v;
#pragma unroll
        for (int e = 0; e < 8; ++e) v[e] = (__bf16)U[(size_t)(kb + e) * HID + c];
        ureg[tile][kk] = v;
      }
    }
    const u16* h0s = (const u16*)h0w;
    const int myflag = 8 + xb * 4 + wv;

    for (int t = 0; t < SEQ; ++t) {
      if (lane == 0) poll4(flg + (size_t)t * FSTR + 0);    // L0 waves @ t
      asm volatile("" ::: "memory");
      const u16* hp = h0s + ((size_t)t * BATCH + r16) * HID + kgrp * 8;
      bf16x8 hA[8];
#pragma unroll
      for (int kk = 0; kk < 8; ++kk)
        hA[kk] = *reinterpret_cast<const bf16x8*>(hp + kk * 32);
      f32x4 acc[8];
#pragma unroll
      for (int tile = 0; tile < 8; ++tile) {
        acc[tile][0] = bias[tile]; acc[tile][1] = bias[tile];
        acc[tile][2] = bias[tile]; acc[tile][3] = bias[tile];
      }
#pragma unroll
      for (int kk = 0; kk < 8; ++kk)
#pragma unroll
        for (int tile = 0; tile < 8; ++tile)
          acc[tile] = __builtin_amdgcn_mfma_f32_16x16x32_bf16(hA[kk], ureg[tile][kk], acc[tile], 0, 0, 0);
      // certify previous step (publishes of t-1 drained; h0 loads already waited)
      asm volatile("s_waitcnt vmcnt(0)" ::: "memory");
      if (lane == 0 && t > 0) AS32(&flg[(size_t)(t - 1) * FSTR + myflag], 1u);
      // publish V(t): [t][gatecol][batch] f32, write-through
#pragma unroll
      for (int tile = 0; tile < 8; ++tile) {
        const int gcol = gbase + tile * 16 + r16;
        u64* vp = (u64*)(V + ((size_t)t * 1024 + gcol) * 16 + kgrp * 4);
        AS64(vp,     pk64(acc[tile][0], acc[tile][1]));
        AS64(vp + 1, pk64(acc[tile][2], acc[tile][3]));
      }
    }
    asm volatile("s_waitcnt vmcnt(0)" ::: "memory");
    if (lane == 0) AS32(&flg[(size_t)(SEQ - 1) * FSTR + myflag], 1u);
    return;
  }

  // ================= L0 (bx==0) / L1 (bx==3): block-local recurrence =================
  const int l = (bx == 3);
  const float* xin = l ? V : XU;                 // pre-activation input, bias folded
  u32* hw = l ? h1w : h0w;
  const int flbase = l ? 4 : 0;

  // ---- weight prologue: 128 frags/lane -> 96 reg + 32 LDS ----
  bf16x8 wreg[4][4][REGK];
#pragma unroll
  for (int g = 0; g < 4; ++g)
#pragma unroll
    for (int ct = 0; ct < 4; ++ct) {
      const int col = 64 * wv + ct * 16 + r16;
#pragma unroll
      for (int kk = 0; kk < 8; ++kk) {
        const int kb = kk * 32 + kgrp * 8;
        bf16x8 v;
#pragma unroll
        for (int e = 0; e < 8; ++e) v[e] = (__bf16)Wg[g][(size_t)(kb + e) * HID + col];
        if (kk < REGK) {
          wreg[g][ct][kk] = v;
        } else {
          const int lidx = (g * 4 + ct) * 2 + (kk - REGK);
          *reinterpret_cast<bf16x8*>(smem + (((size_t)(wv * 32 + lidx) * 64 + lane) * 16)) = v;
        }
      }
    }

  float cst[4][4];
#pragma unroll
  for (int ct = 0; ct < 4; ++ct)
#pragma unroll
    for (int r = 0; r < 4; ++r) cst[ct][r] = 0.f;
  const int odd = lane & 1;

  for (int t = 0; t < SEQ; ++t) {
    // raw barrier (lgkm-only drain): guards h LDS t-1 writes vs t reads;
    // does NOT drain global publishes (they drain under this step's compute).
    asm volatile("s_waitcnt lgkmcnt(0)" ::: "memory");
    __builtin_amdgcn_s_barrier();
    __builtin_amdgcn_sched_barrier(0);

    if (l) {
      if (lane == 0) poll8(flg + (size_t)t * FSTR + 8);    // XV waves @ t
      asm volatile("" ::: "memory");
    }

    bf16x8 hA[8];
    if (t > 0) {
      const char* hbase = smem + WLDS_BYTES + ((t - 1) & 1) * HBUF + r16 * HROW + kgrp * 16;
#pragma unroll
      for (int kk = 0; kk < 8; ++kk)
        hA[kk] = *reinterpret_cast<const bf16x8*>(hbase + kk * 64);
    }

    float hv[4][4];
#pragma unroll
    for (int hf2 = 0; hf2 < 2; ++hf2) {
      f32x4 acc[4][2];
#pragma unroll
      for (int g = 0; g < 4; ++g)
#pragma unroll
        for (int c2 = 0; c2 < 2; ++c2) {
          const int ct = hf2 * 2 + c2;
          acc[g][c2] = *reinterpret_cast<const f32x4*>(
              xin + ((size_t)t * 1024 + g * 256 + 64 * wv + ct * 16 + r16) * 16 + kgrp * 4);
        }
      if (t > 0) {
#pragma unroll
        for (int kk = 0; kk < REGK; ++kk)
#pragma unroll
          for (int g = 0; g < 4; ++g)
#pragma unroll
            for (int c2 = 0; c2 < 2; ++c2)
              acc[g][c2] = __builtin_amdgcn_mfma_f32_16x16x32_bf16(
                  hA[kk], wreg[g][hf2 * 2 + c2][kk], acc[g][c2], 0, 0, 0);
#pragma unroll
        for (int kk = REGK; kk < 8; ++kk)
#pragma unroll
          for (int g = 0; g < 4; ++g)
#pragma unroll
            for (int c2 = 0; c2 < 2; ++c2) {
              const int lidx = (g * 4 + (hf2 * 2 + c2)) * 2 + (kk - REGK);
              const bf16x8 wt = *reinterpret_cast<const bf16x8*>(
                  smem + (((size_t)(wv * 32 + lidx) * 64 + lane) * 16));
              acc[g][c2] = __builtin_amdgcn_mfma_f32_16x16x32_bf16(hA[kk], wt, acc[g][c2], 0, 0, 0);
            }
      }
      // epilogue for this half (all lane-local)
#pragma unroll
      for (int c2 = 0; c2 < 2; ++c2) {
        const int ct = hf2 * 2 + c2;
#pragma unroll
        for (int r = 0; r < 4; ++r) {
          const float f = fsig(acc[0][c2][r]);
          const float i = fsig(acc[1][c2][r]);
          const float g = ftanh(acc[2][c2][r]);
          const float o = fsig(acc[3][c2][r]);
          cst[ct][r] = f * cst[ct][r] + i * g;
          hv[ct][r] = o * ftanh(cst[ct][r]);
        }
      }
    }

    // certify step t-1 (vmcnt(0) is ~free here: this step's loads already waited)
    asm volatile("s_waitcnt vmcnt(0)" ::: "memory");
    if (t > 0 && lane == 0) AS32(&flg[(size_t)(t - 1) * FSTR + flbase + wv], 1u);

    // h(t) -> LDS (next step's A) + global publish (consumers) + final outputs
    {
      char* hdst = smem + WLDS_BYTES + (t & 1) * HBUF;
#pragma unroll
      for (int ct = 0; ct < 4; ++ct)
#pragma unroll
        for (int r = 0; r < 4; ++r) {
          const int col = 64 * wv + ct * 16 + r16;
          const u16 hb = __builtin_bit_cast(u16, (__bf16)hv[ct][r]);
          *reinterpret_cast<u16*>(hdst + (kgrp * 4 + r) * HROW + col * 2) = hb;
          const float ph = __shfl_xor(hv[ct][r], 1);
          const u16 pb = __builtin_bit_cast(u16, (__bf16)ph);
          const u32 pk = odd ? ((u32)pb | ((u32)hb << 16)) : ((u32)hb | ((u32)pb << 16));
          if ((r & 1) == odd)
            AS32(hw + ((size_t)t * BATCH + kgrp * 4 + r) * 128 + (col >> 1), pk);
        }
      if (t == SEQ - 1) {
#pragma unroll
        for (int ct = 0; ct < 4; ++ct)
#pragma unroll
          for (int r = 0; r < 4; ++r) {
            const int col = 64 * wv + ct * 16 + r16;
            const int b = kgrp * 4 + r;
            dout[logitsN + (size_t)(l * BATCH + b) * HID + col] = hv[ct][r];
            dout[logitsN + (size_t)NLAYER * BATCH * HID + (size_t)(l * BATCH + b) * HID + col] = cst[ct][r];
          }
      }
    }
  }
  asm volatile("s_waitcnt vmcnt(0)" ::: "memory");
  if (lane == 0) AS32(&flg[(size_t)(SEQ - 1) * FSTR + flbase + wv], 1u);
}

extern "C" void kernel_launch(void* const* d_in, const int* in_sizes, int n_in,
                              void* d_out, int out_size, void* d_ws, size_t ws_size,
                              hipStream_t stream) {
  const int*   tokp = (const int*)d_in[0];
  const float* embp = (const float*)d_in[1];
  const float* wF = (const float*)d_in[2];
  const float* uF = (const float*)d_in[3];
  const float* bF = (const float*)d_in[4];
  const float* wI = (const float*)d_in[5];
  const float* uI = (const float*)d_in[6];
  const float* bI = (const float*)d_in[7];
  const float* wC = (const float*)d_in[8];
  const float* uC = (const float*)d_in[9];
  const float* bC = (const float*)d_in[10];
  const float* wO = (const float*)d_in[11];
  const float* uO = (const float*)d_in[12];
  const float* bO = (const float*)d_in[13];
  const float* dw = (const float*)d_in[14];
  const float* db = (const float*)d_in[15];
  float* out = (float*)d_out;

  char* ws = (char*)d_ws;
  size_t off = 0;
  float* XU = (float*)(ws + off); off += (size_t)SEQ * 1024 * BATCH * 4;   // 8 MB, [t][gcol][b]
  float* V  = (float*)(ws + off); off += (size_t)SEQ * 1024 * BATCH * 4;   // 8 MB, [t][gcol][b]
  u32* h0w = (u32*)(ws + off); off += (size_t)SEQ * BATCH * HID * 2;       // bf16 h0
  u32* h1w = (u32*)(ws + off); off += (size_t)SEQ * BATCH * HID * 2;       // bf16 h1
  u32* flg = (u32*)(ws + off); off += (size_t)SEQ * FSTR * 4;

  // zero flags -> xu (transposed XU, bias folded) ->
  // mega: L0 | XV0 | XV1 | L1 | 6304 dec blocks (mb-major)
  zero_kernel<<<1, 256, 0, stream>>>(flg);
  xu_kernel<<<dim3(SEQ, 4), 256, 0, stream>>>(tokp, embp, uF, uI, uC, uO,
                                              bF, bI, bC, bO, XU);
  mega_kernel<<<4 + DECBLKS, 256, SMEM_BYTES, stream>>>(
      wF, wI, wC, wO, uF, uI, uC, uO, bF, bI, bC, bO,
      XU, V, h0w, h1w, flg, dw, db, out);
}

// Round 15
// 850.692 us; speedup vs baseline: 1.9144x; 1.9144x over previous
//
#include <hip/hip_runtime.h>
#include <hip/hip_bf16.h>

#define NVOC 50257
#define DIM 256
#define HID 256
#define NLAYER 2
#define SEQ 128
#define BATCH 16
#define GUARD (1 << 20)
#define NCHUNK 197                   // ceil(NVOC/256)
#define DECBLKS (32 * NCHUNK)

typedef __bf16 bf16x8 __attribute__((ext_vector_type(8)));
typedef float f32x4 __attribute__((ext_vector_type(4)));
typedef unsigned short u16;
typedef unsigned int u32;
typedef unsigned long long u64;

#define AL64(p)   __hip_atomic_load((const u64*)(p), __ATOMIC_RELAXED, __HIP_MEMORY_SCOPE_AGENT)
#define AS32(p,v) __hip_atomic_store((u32*)(p), (v), __ATOMIC_RELAXED, __HIP_MEMORY_SCOPE_AGENT)
#define AS64(p,v) __hip_atomic_store((u64*)(p), (v), __ATOMIC_RELAXED, __HIP_MEMORY_SCOPE_AGENT)

__device__ __forceinline__ float fsig(float z) { return 1.f / (1.f + __expf(-z)); }
__device__ __forceinline__ float ftanh(float z) {
  const float x = fminf(fmaxf(z, -15.f), 15.f);
  const float e = __expf(2.f * x);
  return (e - 1.f) / (e + 1.f);
}
__device__ __forceinline__ bf16x8 cvt8(const float4 u0, const float4 u1) {
  bf16x8 v;
  v[0] = (__bf16)u0.x; v[1] = (__bf16)u0.y; v[2] = (__bf16)u0.z; v[3] = (__bf16)u0.w;
  v[4] = (__bf16)u1.x; v[5] = (__bf16)u1.y; v[6] = (__bf16)u1.z; v[7] = (__bf16)u1.w;
  return v;
}

// ---------------- flag zero (before mega each call: replay/poison-safe) ----------------
__global__ void zero_kernel(u32* __restrict__ flg) {
  for (int i = threadIdx.x; i < SEQ * 8; i += 256) AS32(&flg[i], 0u);
}

// ---------------- XU precompute (layer-0 bias folded in) ----------------
// XU[t*16+b][g*256+c] = emb[tok[t,b]] @ U_g + b_g. Grid (128,4) x 256 thr.
__global__ __launch_bounds__(256) void xu_kernel(
    const int* __restrict__ tokp, const float* __restrict__ embp,
    const float* __restrict__ uF, const float* __restrict__ uI,
    const float* __restrict__ uC, const float* __restrict__ uO,
    const float* __restrict__ bF, const float* __restrict__ bI,
    const float* __restrict__ bC, const float* __restrict__ bO,
    float* __restrict__ XU)
{
  const int tid = threadIdx.x;
  const int lane = tid & 63, wv = tid >> 6, r16 = lane & 15, kgrp = lane >> 4;
  const int m0 = blockIdx.x * 16;
  const int n0 = blockIdx.y * 256 + wv * 64;
  const float* Ug[4] = {uF, uI, uC, uO};
  const float* Bp[4] = {bF, bI, bC, bO};

  bf16x8 b[4][8];
  float bias[4];
#pragma unroll
  for (int nt = 0; nt < 4; ++nt) {
    const int n = n0 + nt * 16 + r16;
    const float* U = Ug[n >> 8];
    const int c = n & 255;
    bias[nt] = Bp[n >> 8][c];
#pragma unroll
    for (int kk = 0; kk < 8; ++kk) {
      const int kb = kk * 32 + kgrp * 8;
      bf16x8 v;
#pragma unroll
      for (int e = 0; e < 8; ++e) v[e] = (__bf16)U[(size_t)(kb + e) * HID + c];
      b[nt][kk] = v;
    }
  }

  const int tok = tokp[m0 + r16];
  const float* x = embp + (size_t)tok * DIM;
  bf16x8 a[8];
#pragma unroll
  for (int kk = 0; kk < 8; ++kk) {
    const int kb = kk * 32 + kgrp * 8;
    a[kk] = cvt8(*reinterpret_cast<const float4*>(x + kb),
                 *reinterpret_cast<const float4*>(x + kb + 4));
  }
#pragma unroll
  for (int nt = 0; nt < 4; ++nt) {
    f32x4 acc = {0.f, 0.f, 0.f, 0.f};
#pragma unroll
    for (int kk = 0; kk < 8; ++kk)
      acc = __builtin_amdgcn_mfma_f32_16x16x32_bf16(a[kk], b[nt][kk], acc, 0, 0, 0);
    const int n = n0 + nt * 16 + r16;
#pragma unroll
    for (int r = 0; r < 4; ++r)
      XU[(size_t)(m0 + kgrp * 4 + r) * 1024 + n] = acc[r] + bias[nt];
  }
}

// ---------------- mega kernel: LSTM (bx 0..7) + fused decoder (bx 8..) ----------------
// LSTM: R10 structure (XU-hoist L0, split-wait L1) + u64 packed publish; busy polls.
// DEC:  mb-major ordering + s_sleep(64) backoff.
__global__ __launch_bounds__(512, 2) void mega_kernel(
    const float* __restrict__ wF, const float* __restrict__ wI,
    const float* __restrict__ wC, const float* __restrict__ wO,
    const float* __restrict__ uF, const float* __restrict__ uI,
    const float* __restrict__ uC, const float* __restrict__ uO,
    const float* __restrict__ bF, const float* __restrict__ bI,
    const float* __restrict__ bC, const float* __restrict__ bO,
    const float* __restrict__ XU, u32* __restrict__ h0w, u32* __restrict__ h1w,
    u32* __restrict__ flg, const float* __restrict__ dw,
    const float* __restrict__ dbp, float* __restrict__ dout)
{
  const int tid  = threadIdx.x;
  const int lane = tid & 63;
  const int wv   = tid >> 6;        // 0..7
  const int r16  = lane & 15;
  const int kgrp = lane >> 4;
  const int bx   = blockIdx.x;

  __shared__ float gbuf[4][16][72];

  if (bx >= 8) {
    // ================= decoder block (mb-major) =================
    const int db = bx - 8;
    const int mb = db / NCHUNK;      // m-chunk: rows [mb*64, +64) = t 4mb..4mb+3
    const int nb = db - mb * NCHUNK; // vocab chunk: cols [nb*256, +256)
    const int n0 = nb * 256 + wv * 32;

    bf16x8 b[2][8];
    float bb[2];
#pragma unroll
    for (int nt = 0; nt < 2; ++nt) {
      const int v = n0 + nt * 16 + r16;
      const int vc = (v < NVOC) ? v : (NVOC - 1);
      bb[nt] = dbp[vc];
      const float* bp = dw + (size_t)vc * HID + kgrp * 8;
#pragma unroll
      for (int kk = 0; kk < 8; ++kk)
        b[nt][kk] = cvt8(*reinterpret_cast<const float4*>(bp + kk * 32),
                         *reinterpret_cast<const float4*>(bp + kk * 32 + 4));
    }

    if (tid == 0) {
      const int tl = mb * 4 + 3;
      int gd = 0;
      for (;;) {
        const u64 f0 = AL64(flg + (size_t)tl * 8 + 4);
        const u64 f1 = AL64(flg + (size_t)tl * 8 + 6);
        if (((u32)f0 & (u32)(f0 >> 32) & (u32)f1 & (u32)(f1 >> 32)) != 0u) break;
        if (++gd >= GUARD) break;
        __builtin_amdgcn_s_sleep(64);
      }
    }
    __syncthreads();

    const u16* htb = (const u16*)h1w;
    bf16x8 a[4][8];
#pragma unroll
    for (int mt = 0; mt < 4; ++mt) {
      const u16* ap = htb + ((size_t)(mb * 64 + mt * 16 + r16)) * HID + kgrp * 8;
#pragma unroll
      for (int kk = 0; kk < 8; ++kk)
        a[mt][kk] = *reinterpret_cast<const bf16x8*>(ap + kk * 32);
    }

    f32x4 acc[4][2];
#pragma unroll
    for (int mt = 0; mt < 4; ++mt)
#pragma unroll
      for (int nt = 0; nt < 2; ++nt) {
        acc[mt][nt][0] = 0.f; acc[mt][nt][1] = 0.f;
        acc[mt][nt][2] = 0.f; acc[mt][nt][3] = 0.f;
      }
#pragma unroll
    for (int kk = 0; kk < 8; ++kk)
#pragma unroll
      for (int nt = 0; nt < 2; ++nt) {
        const bf16x8 bv = b[nt][kk];
#pragma unroll
        for (int mt = 0; mt < 4; ++mt)
          acc[mt][nt] = __builtin_amdgcn_mfma_f32_16x16x32_bf16(a[mt][kk], bv, acc[mt][nt], 0, 0, 0);
      }

#pragma unroll
    for (int nt = 0; nt < 2; ++nt) {
      const int v = n0 + nt * 16 + r16;
      if (v < NVOC) {
#pragma unroll
        for (int mt = 0; mt < 4; ++mt)
#pragma unroll
          for (int r = 0; r < 4; ++r)
            dout[(size_t)(mb * 64 + mt * 16 + kgrp * 4 + r) * NVOC + v] = acc[mt][nt][r] + bb[nt];
      }
    }
    return;
  }

  // ================= LSTM blocks =================
  const int colt = wv & 3;
  const int gp   = wv >> 2;
  const int l    = bx >> 2;
  const int jj   = bx & 3;
  const int n    = jj * 64 + colt * 16 + r16;
  const int g0   = gp * 2;

  const float* Wg[4] = {wF, wI, wC, wO};
  const float* Ug[4] = {uF, uI, uC, uO};
  const float* Bg[4] = {bF, bI, bC, bO};
  const u16* h0s = (const u16*)h0w;
  const u16* h1s = (const u16*)h1w;
  const size_t logitsN = (size_t)SEQ * BATCH * NVOC;

  bf16x8 wa[2][8];
  bf16x8 wb[2][8];
  float bias[2];
#pragma unroll
  for (int gi = 0; gi < 2; ++gi) {
    const int g = g0 + gi;
    bias[gi] = Bg[g][n];
#pragma unroll
    for (int kk = 0; kk < 8; ++kk) {
      const int kb = kk * 32 + kgrp * 8;
      bf16x8 v;
#pragma unroll
      for (int e = 0; e < 8; ++e) v[e] = (__bf16)Wg[g][(size_t)(kb + e) * HID + n];
      wa[gi][kk] = v;
      if (l == 1) {
        bf16x8 u;
#pragma unroll
        for (int e = 0; e < 8; ++e) u[e] = (__bf16)Ug[g][(size_t)(kb + e) * HID + n];
        wb[gi][kk] = u;
      }
    }
  }

  // epilogue: 4 cols/thread, 256 active threads, one u64 publish each
  const int eb4 = tid >> 4;          // batch 0..15 (tid < 256)
  const int ec4 = (tid & 15) * 4;    // col group within [0,64)
  float cst[4] = {0.f, 0.f, 0.f, 0.f};

  for (int t = 0; t < SEQ; ++t) {
    f32x4 acc[2];
#pragma unroll
    for (int gi = 0; gi < 2; ++gi) { acc[gi][0]=0.f; acc[gi][1]=0.f; acc[gi][2]=0.f; acc[gi][3]=0.f; }

    float xuv[2][4];
    if (l == 0) {
      // ---- XU hoist: no flag dependency; latency hides under the poll ----
#pragma unroll
      for (int gi = 0; gi < 2; ++gi)
#pragma unroll
        for (int r = 0; r < 4; ++r)
          xuv[gi][r] = XU[(size_t)(t * 16 + kgrp * 4 + r) * 1024 + (g0 + gi) * 256 + n];

      if (t > 0) {
        if (tid == 0) {
          int gd = 0;
          for (;;) {
            const u64 f0 = AL64(flg + (size_t)(t - 1) * 8);
            const u64 f1 = AL64(flg + (size_t)(t - 1) * 8 + 2);
            if (((u32)f0 & (u32)(f0 >> 32) & (u32)f1 & (u32)(f1 >> 32)) != 0u) break;
            if (++gd >= GUARD) break;
          }
        }
        __syncthreads();
        const u16* hp = h0s + ((size_t)(t - 1) * BATCH + r16) * HID + kgrp * 8;
        bf16x8 hA[8];
#pragma unroll
        for (int kk = 0; kk < 8; ++kk)
          hA[kk] = *reinterpret_cast<const bf16x8*>(hp + kk * 32);
#pragma unroll
        for (int kk = 0; kk < 8; ++kk)
#pragma unroll
          for (int gi = 0; gi < 2; ++gi)
            acc[gi] = __builtin_amdgcn_mfma_f32_16x16x32_bf16(hA[kk], wa[gi][kk], acc[gi], 0, 0, 0);
      }
    } else {
      // ---- split wait 1: own layer flags @ t-1 -> W-part MFMAs ----
      if (t > 0) {
        if (tid == 0) {
          int gd = 0;
          for (;;) {
            const u64 g1 = AL64(flg + (size_t)(t - 1) * 8 + 4);
            const u64 g2 = AL64(flg + (size_t)(t - 1) * 8 + 6);
            if (((u32)g1 & (u32)(g1 >> 32) & (u32)g2 & (u32)(g2 >> 32)) != 0u) break;
            if (++gd >= GUARD) break;
          }
        }
        __syncthreads();
        const u16* hp = h1s + ((size_t)(t - 1) * BATCH + r16) * HID + kgrp * 8;
        bf16x8 hB[8];
#pragma unroll
        for (int kk = 0; kk < 8; ++kk)
          hB[kk] = *reinterpret_cast<const bf16x8*>(hp + kk * 32);
#pragma unroll
        for (int kk = 0; kk < 8; ++kk)
#pragma unroll
          for (int gi = 0; gi < 2; ++gi)
            acc[gi] = __builtin_amdgcn_mfma_f32_16x16x32_bf16(hB[kk], wa[gi][kk], acc[gi], 0, 0, 0);
      }
      // ---- split wait 2: L0 flags @ t -> U-part MFMAs ----
      if (tid == 0) {
        int gd = 0;
        for (;;) {
          const u64 f0 = AL64(flg + (size_t)t * 8);
          const u64 f1 = AL64(flg + (size_t)t * 8 + 2);
          if (((u32)f0 & (u32)(f0 >> 32) & (u32)f1 & (u32)(f1 >> 32)) != 0u) break;
          if (++gd >= GUARD) break;
        }
      }
      __syncthreads();
      const u16* xp = h0s + ((size_t)t * BATCH + r16) * HID + kgrp * 8;
      bf16x8 hA[8];
#pragma unroll
      for (int kk = 0; kk < 8; ++kk)
        hA[kk] = *reinterpret_cast<const bf16x8*>(xp + kk * 32);
#pragma unroll
      for (int kk = 0; kk < 8; ++kk)
#pragma unroll
        for (int gi = 0; gi < 2; ++gi)
          acc[gi] = __builtin_amdgcn_mfma_f32_16x16x32_bf16(hA[kk], wb[gi][kk], acc[gi], 0, 0, 0);
    }

    // ---- activations -> LDS ----
#pragma unroll
    for (int gi = 0; gi < 2; ++gi) {
      const int g = g0 + gi;
#pragma unroll
      for (int r = 0; r < 4; ++r) {
        const float z = acc[gi][r] + ((l == 0) ? xuv[gi][r] : bias[gi]);
        gbuf[g][kgrp * 4 + r][colt * 16 + r16] = (g == 2) ? ftanh(z) : fsig(z);
      }
    }
    __syncthreads();

    // ---- c/h update: 4 cols/thread (tid<256), one u64 publish ----
    if (tid < 256) {
      float hv[4];
#pragma unroll
      for (int j = 0; j < 4; ++j) {
        const float ff = gbuf[0][eb4][ec4 + j];
        const float ii = gbuf[1][eb4][ec4 + j];
        const float gg = gbuf[2][eb4][ec4 + j];
        const float oo = gbuf[3][eb4][ec4 + j];
        cst[j] = ff * cst[j] + ii * gg;
        hv[j] = oo * ftanh(cst[j]);
      }
      const u32 lo = (u32)__builtin_bit_cast(u16, (__bf16)hv[0]) |
                     ((u32)__builtin_bit_cast(u16, (__bf16)hv[1]) << 16);
      const u32 hi = (u32)__builtin_bit_cast(u16, (__bf16)hv[2]) |
                     ((u32)__builtin_bit_cast(u16, (__bf16)hv[3]) << 16);
      u32* hw = l ? h1w : h0w;
      AS64((u64*)(hw + ((size_t)t * BATCH + eb4) * 128 + jj * 32 + (ec4 >> 1)),
           (u64)lo | ((u64)hi << 32));

      if (t == SEQ - 1) {
        const int nn = jj * 64 + ec4;
        float* hT = dout + logitsN + ((size_t)l * BATCH + eb4) * HID + nn;
        float* cT = dout + logitsN + (size_t)NLAYER * BATCH * HID + ((size_t)l * BATCH + eb4) * HID + nn;
#pragma unroll
        for (int j = 0; j < 4; ++j) { hT[j] = hv[j]; cT[j] = cst[j]; }
      }
    }
    __syncthreads();                // vmcnt(0) drain: publishes complete before flag
    if (tid == 0) AS32(&flg[(size_t)t * 8 + l * 4 + jj], 1u);
  }
}

extern "C" void kernel_launch(void* const* d_in, const int* in_sizes, int n_in,
                              void* d_out, int out_size, void* d_ws, size_t ws_size,
                              hipStream_t stream) {
  const int*   tokp = (const int*)d_in[0];
  const float* embp = (const float*)d_in[1];
  const float* wF = (const float*)d_in[2];
  const float* uF = (const float*)d_in[3];
  const float* bF = (const float*)d_in[4];
  const float* wI = (const float*)d_in[5];
  const float* uI = (const float*)d_in[6];
  const float* bI = (const float*)d_in[7];
  const float* wC = (const float*)d_in[8];
  const float* uC = (const float*)d_in[9];
  const float* bC = (const float*)d_in[10];
  const float* wO = (const float*)d_in[11];
  const float* uO = (const float*)d_in[12];
  const float* bO = (const float*)d_in[13];
  const float* dw = (const float*)d_in[14];
  const float* db = (const float*)d_in[15];
  float* out = (float*)d_out;

  char* ws = (char*)d_ws;
  size_t off = 0;
  float* XU = (float*)(ws + off); off += (size_t)SEQ * BATCH * 1024 * 4;   // 8 MB
  u32* h0w = (u32*)(ws + off); off += (size_t)SEQ * BATCH * HID * 2;       // bf16 h0
  u32* h1w = (u32*)(ws + off); off += (size_t)SEQ * BATCH * HID * 2;       // bf16 h1
  u32* flg = (u32*)(ws + off); off += (size_t)SEQ * 8 * 4;

  // zero (flags, replay-safe) -> xu (XU with L0 bias folded) ->
  // mega: LSTM blocks 0..7 + 6304 decoder blocks (mb-major) consuming h1 as produced.
  zero_kernel<<<1, 256, 0, stream>>>(flg);
  xu_kernel<<<dim3(128, 4), 256, 0, stream>>>(tokp, embp, uF, uI, uC, uO,
                                              bF, bI, bC, bO, XU);
  mega_kernel<<<8 + DECBLKS, 512, 0, stream>>>(wF, wI, wC, wO, uF, uI, uC, uO,
                                               bF, bI, bC, bO, XU, h0w, h1w, flg,
                                               dw, db, out);
}